// Round 1
// baseline (7817.603 us; speedup 1.0000x reference)
//
#include <hip/hip_runtime.h>

#define L_DIM 16
#define N_DIM 200000
#define M_DIM 100000
#define F_DIM 7
#define H_DIM 64
#define RT 64    // rows per block in step kernel
#define BT 512   // threads in step kernel

// ---------------------------------------------------------------------------
// u = tanh(contents_l @ Wu.T + bu)  for all N rows -> out (N,64)
// thread per output element; Wu/bu staged in LDS.
// ---------------------------------------------------------------------------
__global__ __launch_bounds__(256) void u_kernel(const float* __restrict__ contents_l,
                                                const float* __restrict__ Wu,
                                                const float* __restrict__ bu,
                                                float* __restrict__ out) {
    __shared__ float sWu[H_DIM * F_DIM];
    __shared__ float sbu[H_DIM];
    int t = threadIdx.x;
    for (int idx = t; idx < H_DIM * F_DIM; idx += 256) sWu[idx] = Wu[idx];
    if (t < H_DIM) sbu[t] = bu[t];
    __syncthreads();

    int gid = blockIdx.x * 256 + t;
    int i = gid >> 6;
    int h = gid & 63;
    if (i >= N_DIM) return;
    const float* c = contents_l + (size_t)i * F_DIM;
    float acc = sbu[h];
#pragma unroll
    for (int f = 0; f < F_DIM; ++f) acc = fmaf(c[f], sWu[h * F_DIM + f], acc);
    out[(size_t)i * H_DIM + h] = tanhf(acc);
}

// ---------------------------------------------------------------------------
// WT[c*R + r] = W[r*C + c]   (W is R x C row-major; WT is C x R row-major)
// ---------------------------------------------------------------------------
__global__ void transpose_kernel(const float* __restrict__ W, float* __restrict__ WT,
                                 int R, int C) {
    int idx = blockIdx.x * 256 + threadIdx.x;
    if (idx >= R * C) return;
    int r = idx / C, c = idx % C;
    WT[c * R + r] = W[r * C + c];
}

// ---------------------------------------------------------------------------
// One scan step over M rows.
//   embP: previous embedding (N,64)   [read-only]
//   embC: current buffer (N,64); rows<M hold u_in on entry, h on exit
//   chl : children for this step (M,2) int32
//   WrT : (192k x 192j), WhT: (192k x 64j), WzT: (256k x 256j)
// Block: 512 threads = (c in [0,64)) x (rg in [0,8)); RT=64 rows per block.
// ---------------------------------------------------------------------------
__global__ __launch_bounds__(BT) void step_kernel(
    const float* __restrict__ embP,
    float* __restrict__ embC,
    const int* __restrict__ chl,
    const float* __restrict__ WrT, const float* __restrict__ br,
    const float* __restrict__ WhT, const float* __restrict__ bh,
    const float* __restrict__ WzT, const float* __restrict__ bz)
{
    __shared__ __align__(16) float hhu[RT][196];
    __shared__ __align__(16) float rh[RT][196];
    __shared__ __align__(16) float hH[RT][68];

    int t = threadIdx.x;
    int c = t & 63;
    int rg = t >> 6;                 // 0..7
    int base = blockIdx.x * RT;
    int nrows = M_DIM - base; if (nrows > RT) nrows = RT;

    // ---- Phase 0: gather hhu = [h_L | h_R | u_in] ----
#pragma unroll
    for (int j = 0; j < 8; ++j) {
        int r = rg * 8 + j;
        int i = base + r;
        if (r < nrows) {
            int iL = chl[i * 2 + 0];
            int iR = chl[i * 2 + 1];
            hhu[r][c]       = embP[iL * 64 + c];
            hhu[r][64 + c]  = embP[iR * 64 + c];
            hhu[r][128 + c] = embC[i * 64 + c];
        } else {
            hhu[r][c] = 0.f; hhu[r][64 + c] = 0.f; hhu[r][128 + c] = 0.f;
        }
    }
    __syncthreads();

    // ---- Phase 1: r = sigmoid(hhu @ Wr.T + br); rh = r * hhu ----
    {
        float acc[8][3];
#pragma unroll
        for (int j = 0; j < 8; ++j) { acc[j][0] = 0.f; acc[j][1] = 0.f; acc[j][2] = 0.f; }
        for (int k = 0; k < 192; k += 4) {
            float w[4][3];
#pragma unroll
            for (int kk = 0; kk < 4; ++kk) {
                w[kk][0] = WrT[(k + kk) * 192 + c];
                w[kk][1] = WrT[(k + kk) * 192 + 64 + c];
                w[kk][2] = WrT[(k + kk) * 192 + 128 + c];
            }
#pragma unroll
            for (int j = 0; j < 8; ++j) {
                float4 a = *(const float4*)&hhu[rg * 8 + j][k];
                acc[j][0] = fmaf(a.x, w[0][0], acc[j][0]);
                acc[j][1] = fmaf(a.x, w[0][1], acc[j][1]);
                acc[j][2] = fmaf(a.x, w[0][2], acc[j][2]);
                acc[j][0] = fmaf(a.y, w[1][0], acc[j][0]);
                acc[j][1] = fmaf(a.y, w[1][1], acc[j][1]);
                acc[j][2] = fmaf(a.y, w[1][2], acc[j][2]);
                acc[j][0] = fmaf(a.z, w[2][0], acc[j][0]);
                acc[j][1] = fmaf(a.z, w[2][1], acc[j][1]);
                acc[j][2] = fmaf(a.z, w[2][2], acc[j][2]);
                acc[j][0] = fmaf(a.w, w[3][0], acc[j][0]);
                acc[j][1] = fmaf(a.w, w[3][1], acc[j][1]);
                acc[j][2] = fmaf(a.w, w[3][2], acc[j][2]);
            }
        }
#pragma unroll
        for (int j = 0; j < 8; ++j) {
            int r = rg * 8 + j;
#pragma unroll
            for (int ch = 0; ch < 3; ++ch) {
                float x = acc[j][ch] + br[ch * 64 + c];
                float rv = 1.f / (1.f + expf(-x));
                rh[r][ch * 64 + c] = rv * hhu[r][ch * 64 + c];
            }
        }
    }
    __syncthreads();

    // ---- Phase 2: h_H = tanh(rh @ Wh.T + bh) ----
    {
        float acc2[8];
#pragma unroll
        for (int j = 0; j < 8; ++j) acc2[j] = 0.f;
        for (int k = 0; k < 192; k += 4) {
            float w0 = WhT[(k + 0) * 64 + c];
            float w1 = WhT[(k + 1) * 64 + c];
            float w2 = WhT[(k + 2) * 64 + c];
            float w3 = WhT[(k + 3) * 64 + c];
#pragma unroll
            for (int j = 0; j < 8; ++j) {
                float4 a = *(const float4*)&rh[rg * 8 + j][k];
                acc2[j] = fmaf(a.x, w0, acc2[j]);
                acc2[j] = fmaf(a.y, w1, acc2[j]);
                acc2[j] = fmaf(a.z, w2, acc2[j]);
                acc2[j] = fmaf(a.w, w3, acc2[j]);
            }
        }
#pragma unroll
        for (int j = 0; j < 8; ++j) hH[rg * 8 + j][c] = tanhf(acc2[j] + bh[c]);
    }
    __syncthreads();

    // ---- Phase 3: z = [h_H | hhu] @ Wz.T + bz; gate softmax; h; write ----
    {
        float accz[8][4];
#pragma unroll
        for (int j = 0; j < 8; ++j) { accz[j][0] = accz[j][1] = accz[j][2] = accz[j][3] = 0.f; }
        // k in [0,64): h_H part
        for (int k = 0; k < 64; k += 4) {
            float w[4][4];
#pragma unroll
            for (int kk = 0; kk < 4; ++kk) {
#pragma unroll
                for (int g = 0; g < 4; ++g)
                    w[kk][g] = WzT[(k + kk) * 256 + g * 64 + c];
            }
#pragma unroll
            for (int j = 0; j < 8; ++j) {
                float4 a = *(const float4*)&hH[rg * 8 + j][k];
#pragma unroll
                for (int g = 0; g < 4; ++g) {
                    accz[j][g] = fmaf(a.x, w[0][g], accz[j][g]);
                    accz[j][g] = fmaf(a.y, w[1][g], accz[j][g]);
                    accz[j][g] = fmaf(a.z, w[2][g], accz[j][g]);
                    accz[j][g] = fmaf(a.w, w[3][g], accz[j][g]);
                }
            }
        }
        // k in [64,256): hhu part
        for (int k = 0; k < 192; k += 4) {
            float w[4][4];
#pragma unroll
            for (int kk = 0; kk < 4; ++kk) {
#pragma unroll
                for (int g = 0; g < 4; ++g)
                    w[kk][g] = WzT[(64 + k + kk) * 256 + g * 64 + c];
            }
#pragma unroll
            for (int j = 0; j < 8; ++j) {
                float4 a = *(const float4*)&hhu[rg * 8 + j][k];
#pragma unroll
                for (int g = 0; g < 4; ++g) {
                    accz[j][g] = fmaf(a.x, w[0][g], accz[j][g]);
                    accz[j][g] = fmaf(a.y, w[1][g], accz[j][g]);
                    accz[j][g] = fmaf(a.z, w[2][g], accz[j][g]);
                    accz[j][g] = fmaf(a.w, w[3][g], accz[j][g]);
                }
            }
        }
#pragma unroll
        for (int j = 0; j < 8; ++j) {
            int r = rg * 8 + j;
            int i = base + r;
            if (r < nrows) {
                float z0 = accz[j][0] + bz[c];
                float z1 = accz[j][1] + bz[64 + c];
                float z2 = accz[j][2] + bz[128 + c];
                float z3 = accz[j][3] + bz[192 + c];
                float mx = fmaxf(fmaxf(z0, z1), fmaxf(z2, z3));
                float e0 = expf(z0 - mx), e1 = expf(z1 - mx);
                float e2 = expf(z2 - mx), e3 = expf(z3 - mx);
                float s = e0 + e1 + e2 + e3;
                float h = (e0 * hH[r][c] + e1 * hhu[r][c] + e2 * hhu[r][64 + c]
                           + e3 * hhu[r][128 + c]) / s;
                embC[i * 64 + c] = h;
            }
        }
    }
}

// ---------------------------------------------------------------------------
extern "C" void kernel_launch(void* const* d_in, const int* in_sizes, int n_in,
                              void* d_out, int out_size, void* d_ws, size_t ws_size,
                              hipStream_t stream) {
    const float* contents = (const float*)d_in[0];
    const int*   children = (const int*)d_in[1];
    const float* Wu = (const float*)d_in[2];
    const float* bu = (const float*)d_in[3];
    const float* Wh = (const float*)d_in[4];
    const float* bh = (const float*)d_in[5];
    const float* Wz = (const float*)d_in[6];
    const float* bz = (const float*)d_in[7];
    const float* Wr = (const float*)d_in[8];
    const float* br = (const float*)d_in[9];
    float* out = (float*)d_out;
    float* ws  = (float*)d_ws;

    float* embEven = ws;                               // N*64 floats (after even steps)
    float* WrT = ws + (size_t)N_DIM * H_DIM;           // 192*192
    float* WhT = WrT + 192 * 192;                      // 192*64
    float* WzT = WhT + 192 * 64;                       // 256*256

    // one-time (per call) weight transposes
    transpose_kernel<<<(192 * 192 + 255) / 256, 256, 0, stream>>>(Wr, WrT, 192, 192);
    transpose_kernel<<<(64 * 192 + 255) / 256, 256, 0, stream>>>(Wh, WhT, 64, 192);
    transpose_kernel<<<(256 * 256 + 255) / 256, 256, 0, stream>>>(Wz, WzT, 256, 256);

    int ublocks = (N_DIM * H_DIM + 255) / 256;
    int sblocks = (M_DIM + RT - 1) / RT;

    // emb0 -> embEven
    u_kernel<<<ublocks, 256, 0, stream>>>(contents, Wu, bu, embEven);

    for (int l = 1; l < L_DIM; ++l) {
        float* cur        = (l & 1) ? out : embEven;
        const float* prev = (l & 1) ? embEven : out;
        // u for all N rows into cur (rows >= M final; rows < M = u_in, overwritten below)
        u_kernel<<<ublocks, 256, 0, stream>>>(contents + (size_t)l * N_DIM * F_DIM,
                                              Wu, bu, cur);
        step_kernel<<<sblocks, BT, 0, stream>>>(prev, cur,
                                                children + (size_t)(l - 1) * M_DIM * 2,
                                                WrT, br, WhT, bh, WzT, bz);
    }
}

// Round 2
// 6542.910 us; speedup vs baseline: 1.1948x; 1.1948x over previous
//
#include <hip/hip_runtime.h>

#define L_DIM 16
#define N_DIM 200000
#define M_DIM 100000
#define F_DIM 7
#define H_DIM 64
#define RT 64    // rows per block in step kernel
#define BT 512   // threads in step kernel

// ---------------------------------------------------------------------------
// u = tanh(contents_l @ Wu.T + bu)  for all N rows -> out (N,64)
// ---------------------------------------------------------------------------
__global__ __launch_bounds__(256) void u_kernel(const float* __restrict__ contents_l,
                                                const float* __restrict__ Wu,
                                                const float* __restrict__ bu,
                                                float* __restrict__ out) {
    __shared__ float sWu[H_DIM * F_DIM];
    __shared__ float sbu[H_DIM];
    int t = threadIdx.x;
    for (int idx = t; idx < H_DIM * F_DIM; idx += 256) sWu[idx] = Wu[idx];
    if (t < H_DIM) sbu[t] = bu[t];
    __syncthreads();

    int gid = blockIdx.x * 256 + t;
    int i = gid >> 6;
    int h = gid & 63;
    if (i >= N_DIM) return;
    const float* c = contents_l + (size_t)i * F_DIM;
    float acc = sbu[h];
#pragma unroll
    for (int f = 0; f < F_DIM; ++f) acc = fmaf(c[f], sWu[h * F_DIM + f], acc);
    out[(size_t)i * H_DIM + h] = tanhf(acc);
}

// ---------------------------------------------------------------------------
// Interleaved weight prep:
//  Wri[(k*64+c)*4+q] = (q<3) ? Wr[(q*64+c)*192 + k] : 0      (192*64*4)
//  Whi[(k4*64+c)*4+q] = Wh[c*192 + 4*k4+q]                    (48*64*4)
//  Wzi[(k*64+c)*4+q] = Wz[(q*64+c)*256 + k]                   (256*64*4)
// Lane c then loads ONE float4 per k containing every weight it needs.
// ---------------------------------------------------------------------------
__global__ void prep_weights(const float* __restrict__ Wr, const float* __restrict__ Wh,
                             const float* __restrict__ Wz,
                             float* __restrict__ Wri, float* __restrict__ Whi,
                             float* __restrict__ Wzi) {
    const int NWri = 192 * 64 * 4, NWhi = 48 * 64 * 4, NWzi = 256 * 64 * 4;
    int idx = blockIdx.x * 256 + threadIdx.x;
    if (idx < NWri) {
        int q = idx & 3, c = (idx >> 2) & 63, k = idx >> 8;
        Wri[idx] = (q < 3) ? Wr[(q * 64 + c) * 192 + k] : 0.f;
    } else if (idx < NWri + NWhi) {
        int m = idx - NWri;
        int q = m & 3, c = (m >> 2) & 63, k4 = m >> 8;
        Whi[m] = Wh[c * 192 + 4 * k4 + q];
    } else if (idx < NWri + NWhi + NWzi) {
        int m = idx - NWri - NWhi;
        int q = m & 3, c = (m >> 2) & 63, k = m >> 8;
        Wzi[m] = Wz[(q * 64 + c) * 256 + k];
    }
}

// ---------------------------------------------------------------------------
// One scan step over M rows. 512 thr = (c 0..63) x (rg 0..7), 8 rows/thread.
// LDS: hhu[64][196] (reused for r*hhu after phase 1) + hH[64][64]  = 65 KB.
// ---------------------------------------------------------------------------
__global__ __launch_bounds__(BT, 4) void step_kernel(
    const float* __restrict__ embP,
    float* __restrict__ embC,
    const int* __restrict__ chl,
    const float4* __restrict__ Wri, const float* __restrict__ br,
    const float4* __restrict__ Whi, const float* __restrict__ bh,
    const float4* __restrict__ Wzi, const float* __restrict__ bz)
{
    __shared__ __align__(16) float hhu[RT][196];
    __shared__ __align__(16) float hH[RT][64];

    int t = threadIdx.x;
    int c = t & 63;
    int rg = t >> 6;                 // 0..7
    int base = blockIdx.x * RT;
    int nrows = M_DIM - base; if (nrows > RT) nrows = RT;

    // ---- Phase 0: gather; keep own columns in regs ----
    float hl[8], hr[8], uu[8];
#pragma unroll
    for (int j = 0; j < 8; ++j) {
        int r = rg * 8 + j;
        int i = base + r;
        if (r < nrows) {
            int iL = chl[i * 2 + 0];
            int iR = chl[i * 2 + 1];
            hl[j] = embP[(size_t)iL * 64 + c];
            hr[j] = embP[(size_t)iR * 64 + c];
            uu[j] = embC[(size_t)i * 64 + c];
        } else { hl[j] = hr[j] = uu[j] = 0.f; }
        hhu[r][c]       = hl[j];
        hhu[r][64 + c]  = hr[j];
        hhu[r][128 + c] = uu[j];
    }
    __syncthreads();

    // ---- Phase 1a: accr = hhu @ Wr.T  (3 outputs per lane) ----
    float accr0[8], accr1[8], accr2[8];
#pragma unroll
    for (int j = 0; j < 8; ++j) { accr0[j] = 0.f; accr1[j] = 0.f; accr2[j] = 0.f; }
    for (int k = 0; k < 192; k += 4) {
        float4 w0 = Wri[(k + 0) * 64 + c];
        float4 w1 = Wri[(k + 1) * 64 + c];
        float4 w2 = Wri[(k + 2) * 64 + c];
        float4 w3 = Wri[(k + 3) * 64 + c];
#pragma unroll
        for (int j = 0; j < 8; ++j) {
            float4 a = *(const float4*)&hhu[rg * 8 + j][k];
            accr0[j] = fmaf(a.x, w0.x, accr0[j]);
            accr1[j] = fmaf(a.x, w0.y, accr1[j]);
            accr2[j] = fmaf(a.x, w0.z, accr2[j]);
            accr0[j] = fmaf(a.y, w1.x, accr0[j]);
            accr1[j] = fmaf(a.y, w1.y, accr1[j]);
            accr2[j] = fmaf(a.y, w1.z, accr2[j]);
            accr0[j] = fmaf(a.z, w2.x, accr0[j]);
            accr1[j] = fmaf(a.z, w2.y, accr1[j]);
            accr2[j] = fmaf(a.z, w2.z, accr2[j]);
            accr0[j] = fmaf(a.w, w3.x, accr0[j]);
            accr1[j] = fmaf(a.w, w3.y, accr1[j]);
            accr2[j] = fmaf(a.w, w3.z, accr2[j]);
        }
    }

    // ---- Phase 1b: z partial over hhu columns (k_full = 64..255) ----
    float az0[8], az1[8], az2[8], az3[8];
#pragma unroll
    for (int j = 0; j < 8; ++j) { az0[j] = 0.f; az1[j] = 0.f; az2[j] = 0.f; az3[j] = 0.f; }
    for (int k = 0; k < 192; k += 4) {
        float4 w0 = Wzi[(64 + k + 0) * 64 + c];
        float4 w1 = Wzi[(64 + k + 1) * 64 + c];
        float4 w2 = Wzi[(64 + k + 2) * 64 + c];
        float4 w3 = Wzi[(64 + k + 3) * 64 + c];
#pragma unroll
        for (int j = 0; j < 8; ++j) {
            float4 a = *(const float4*)&hhu[rg * 8 + j][k];
            az0[j] = fmaf(a.x, w0.x, az0[j]);
            az1[j] = fmaf(a.x, w0.y, az1[j]);
            az2[j] = fmaf(a.x, w0.z, az2[j]);
            az3[j] = fmaf(a.x, w0.w, az3[j]);
            az0[j] = fmaf(a.y, w1.x, az0[j]);
            az1[j] = fmaf(a.y, w1.y, az1[j]);
            az2[j] = fmaf(a.y, w1.z, az2[j]);
            az3[j] = fmaf(a.y, w1.w, az3[j]);
            az0[j] = fmaf(a.z, w2.x, az0[j]);
            az1[j] = fmaf(a.z, w2.y, az1[j]);
            az2[j] = fmaf(a.z, w2.z, az2[j]);
            az3[j] = fmaf(a.z, w2.w, az3[j]);
            az0[j] = fmaf(a.w, w3.x, az0[j]);
            az1[j] = fmaf(a.w, w3.y, az1[j]);
            az2[j] = fmaf(a.w, w3.z, az2[j]);
            az3[j] = fmaf(a.w, w3.w, az3[j]);
        }
    }
    __syncthreads();   // everyone done READING hhu

    // ---- overwrite hhu in place with r * hhu ----
#pragma unroll
    for (int j = 0; j < 8; ++j) {
        int r = rg * 8 + j;
        float r0 = 1.f / (1.f + expf(-(accr0[j] + br[c])));
        float r1 = 1.f / (1.f + expf(-(accr1[j] + br[64 + c])));
        float r2 = 1.f / (1.f + expf(-(accr2[j] + br[128 + c])));
        hhu[r][c]       = r0 * hl[j];
        hhu[r][64 + c]  = r1 * hr[j];
        hhu[r][128 + c] = r2 * uu[j];
    }
    __syncthreads();

    // ---- Phase 2: h_H = tanh(rh @ Wh.T + bh) ----
    float hHreg[8];
    {
        float acc2[8];
#pragma unroll
        for (int j = 0; j < 8; ++j) acc2[j] = 0.f;
        for (int k4 = 0; k4 < 48; ++k4) {
            float4 w = Whi[k4 * 64 + c];
#pragma unroll
            for (int j = 0; j < 8; ++j) {
                float4 a = *(const float4*)&hhu[rg * 8 + j][k4 * 4];
                acc2[j] = fmaf(a.x, w.x, acc2[j]);
                acc2[j] = fmaf(a.y, w.y, acc2[j]);
                acc2[j] = fmaf(a.z, w.z, acc2[j]);
                acc2[j] = fmaf(a.w, w.w, acc2[j]);
            }
        }
#pragma unroll
        for (int j = 0; j < 8; ++j) {
            hHreg[j] = tanhf(acc2[j] + bh[c]);
            hH[rg * 8 + j][c] = hHreg[j];
        }
    }
    __syncthreads();

    // ---- Phase 3: z += hH part (k_full = 0..63) ----
    for (int k = 0; k < 64; k += 4) {
        float4 w0 = Wzi[(k + 0) * 64 + c];
        float4 w1 = Wzi[(k + 1) * 64 + c];
        float4 w2 = Wzi[(k + 2) * 64 + c];
        float4 w3 = Wzi[(k + 3) * 64 + c];
#pragma unroll
        for (int j = 0; j < 8; ++j) {
            float4 a = *(const float4*)&hH[rg * 8 + j][k];
            az0[j] = fmaf(a.x, w0.x, az0[j]);
            az1[j] = fmaf(a.x, w0.y, az1[j]);
            az2[j] = fmaf(a.x, w0.z, az2[j]);
            az3[j] = fmaf(a.x, w0.w, az3[j]);
            az0[j] = fmaf(a.y, w1.x, az0[j]);
            az1[j] = fmaf(a.y, w1.y, az1[j]);
            az2[j] = fmaf(a.y, w1.z, az2[j]);
            az3[j] = fmaf(a.y, w1.w, az3[j]);
            az0[j] = fmaf(a.z, w2.x, az0[j]);
            az1[j] = fmaf(a.z, w2.y, az1[j]);
            az2[j] = fmaf(a.z, w2.z, az2[j]);
            az3[j] = fmaf(a.z, w2.w, az3[j]);
            az0[j] = fmaf(a.w, w3.x, az0[j]);
            az1[j] = fmaf(a.w, w3.y, az1[j]);
            az2[j] = fmaf(a.w, w3.z, az2[j]);
            az3[j] = fmaf(a.w, w3.w, az3[j]);
        }
    }

    // ---- epilogue: gate softmax + mix + write ----
#pragma unroll
    for (int j = 0; j < 8; ++j) {
        int r = rg * 8 + j;
        int i = base + r;
        if (r < nrows) {
            float z0 = az0[j] + bz[c];
            float z1 = az1[j] + bz[64 + c];
            float z2 = az2[j] + bz[128 + c];
            float z3 = az3[j] + bz[192 + c];
            float mx = fmaxf(fmaxf(z0, z1), fmaxf(z2, z3));
            float e0 = expf(z0 - mx), e1 = expf(z1 - mx);
            float e2 = expf(z2 - mx), e3 = expf(z3 - mx);
            float s = e0 + e1 + e2 + e3;
            float h = (e0 * hHreg[j] + e1 * hl[j] + e2 * hr[j] + e3 * uu[j]) / s;
            embC[(size_t)i * 64 + c] = h;
        }
    }
}

// ---------------------------------------------------------------------------
extern "C" void kernel_launch(void* const* d_in, const int* in_sizes, int n_in,
                              void* d_out, int out_size, void* d_ws, size_t ws_size,
                              hipStream_t stream) {
    const float* contents = (const float*)d_in[0];
    const int*   children = (const int*)d_in[1];
    const float* Wu = (const float*)d_in[2];
    const float* bu = (const float*)d_in[3];
    const float* Wh = (const float*)d_in[4];
    const float* bh = (const float*)d_in[5];
    const float* Wz = (const float*)d_in[6];
    const float* bz = (const float*)d_in[7];
    const float* Wr = (const float*)d_in[8];
    const float* br = (const float*)d_in[9];
    float* out = (float*)d_out;
    float* ws  = (float*)d_ws;

    float* embEven = ws;                               // N*64 floats
    float* Wri = ws + (size_t)N_DIM * H_DIM;           // 192*64*4
    float* Whi = Wri + 192 * 64 * 4;                   // 48*64*4
    float* Wzi = Whi + 48 * 64 * 4;                    // 256*64*4

    const int NPREP = 192 * 64 * 4 + 48 * 64 * 4 + 256 * 64 * 4;
    prep_weights<<<(NPREP + 255) / 256, 256, 0, stream>>>(Wr, Wh, Wz, Wri, Whi, Wzi);

    int ublocks = (N_DIM * H_DIM + 255) / 256;
    int sblocks = (M_DIM + RT - 1) / RT;

    u_kernel<<<ublocks, 256, 0, stream>>>(contents, Wu, bu, embEven);

    for (int l = 1; l < L_DIM; ++l) {
        float* cur        = (l & 1) ? out : embEven;
        const float* prev = (l & 1) ? embEven : out;
        u_kernel<<<ublocks, 256, 0, stream>>>(contents + (size_t)l * N_DIM * F_DIM,
                                              Wu, bu, cur);
        step_kernel<<<sblocks, BT, 0, stream>>>(prev, cur,
                                                children + (size_t)(l - 1) * M_DIM * 2,
                                                (const float4*)Wri, br,
                                                (const float4*)Whi, bh,
                                                (const float4*)Wzi, bz);
    }
}